// Round 1
// baseline (199.580 us; speedup 1.0000x reference)
//
#include <hip/hip_runtime.h>
#include <stdint.h>
#include <math.h>

#define B_ 2
#define S_ 2048
#define D_ 1024
#define H_ 16
#define DK_ 64
#define M_ (B_*S_)   // 4096

typedef unsigned short u16;
typedef unsigned int u32;
typedef __attribute__((ext_vector_type(8))) __bf16 bf16x8;
typedef __attribute__((ext_vector_type(4))) float f32x4;

#define AS1 __attribute__((address_space(1)))
#define AS3 __attribute__((address_space(3)))

__device__ __forceinline__ u16 f2bf(float f) {
  u32 u = __float_as_uint(f);
  return (u16)((u + 0x7fffu + ((u >> 16) & 1u)) >> 16);  // RNE
}

__device__ __forceinline__ void gload_lds16(const void* g, void* lds) {
  __builtin_amdgcn_global_load_lds((const AS1 u32*)g,
                                   (AS3 u32*)(u32)(uintptr_t)lds, 16, 0, 0);
}

// ---------------- fp32 -> bf16 convert (vectorized) ----------------
__global__ __launch_bounds__(256) void f2bf_kernel(const float* __restrict__ in,
                                                   u16* __restrict__ out, int n4) {
  int i = blockIdx.x * 256 + threadIdx.x;
  if (i >= n4) return;
  float4 v = ((const float4*)in)[i];
  u32 lo = (u32)f2bf(v.x) | ((u32)f2bf(v.y) << 16);
  u32 hi = (u32)f2bf(v.z) | ((u32)f2bf(v.w) << 16);
  ((uint2*)out)[i] = make_uint2(lo, hi);
}

// ---------------- GEMM: C[m,n] = sum_k A[m,k]*W[n,k] + bias[n] ----------------
// A:[M,K] bf16 row-major, W:[N,K] bf16 row-major (torch Linear layout).
// 128x128 tile, BK=32, 4 waves (each 64x64 = 4x4 fragments of 16x16x32).
template <bool OUT_F32, bool QKV>
__global__ __launch_bounds__(256) void gemm_bt(
    const u16* __restrict__ A,
    const u16* __restrict__ W0, const u16* __restrict__ W1, const u16* __restrict__ W2,
    const float* __restrict__ b0, const float* __restrict__ b1, const float* __restrict__ b2,
    void* __restrict__ C0, void* __restrict__ C1, void* __restrict__ C2,
    int M, int N, int K) {
  const u16* W = W0; const float* bias = b0; void* Cv = C0;
  if (QKV) {
    if (blockIdx.z == 1)      { W = W1; bias = b1; Cv = C1; }
    else if (blockIdx.z == 2) { W = W2; bias = b2; Cv = C2; }
  }
  __shared__ u16 As[128*32];
  __shared__ u16 Bs[128*32];
  const int tid = threadIdx.x;
  const int wave = tid >> 6, lane = tid & 63;
  const int lo = lane & 15, hi = lane >> 4;
  const int wr = wave >> 1, wc = wave & 1;
  const int mbase = blockIdx.y * 128, nbase = blockIdx.x * 128;

  f32x4 acc[4][4] = {};

  for (int k0 = 0; k0 < K; k0 += 32) {
#pragma unroll
    for (int i = 0; i < 2; ++i) {
      int row = i*64 + (tid >> 2);
      int col = (tid & 3) * 8;
      gload_lds16(&A[(size_t)(mbase + row)*K + k0 + col], &As[row*32 + col]);
      gload_lds16(&W[(size_t)(nbase + row)*K + k0 + col], &Bs[row*32 + col]);
    }
    __syncthreads();
    bf16x8 af[4], bfr[4];
#pragma unroll
    for (int m = 0; m < 4; ++m)
      af[m] = *(const bf16x8*)&As[(wr*64 + m*16 + lo)*32 + hi*8];
#pragma unroll
    for (int n = 0; n < 4; ++n)
      bfr[n] = *(const bf16x8*)&Bs[(wc*64 + n*16 + lo)*32 + hi*8];
#pragma unroll
    for (int m = 0; m < 4; ++m)
#pragma unroll
      for (int n = 0; n < 4; ++n)
        acc[m][n] = __builtin_amdgcn_mfma_f32_16x16x32_bf16(af[m], bfr[n], acc[m][n], 0, 0, 0);
    __syncthreads();
  }

#pragma unroll
  for (int n = 0; n < 4; ++n) {
    int col = nbase + wc*64 + n*16 + lo;
    float bv = bias[col];
#pragma unroll
    for (int m = 0; m < 4; ++m) {
#pragma unroll
      for (int j = 0; j < 4; ++j) {
        int row = mbase + wr*64 + m*16 + hi*4 + j;
        float v = acc[m][n][j] + bv;
        if constexpr (OUT_F32) ((float*)Cv)[(size_t)row*N + col] = v;
        else                   ((u16*)Cv)[(size_t)row*N + col] = f2bf(v);
      }
    }
  }
}

// ---------------- V [B,S,H,DK] -> Vt [B,H,DK,S] ----------------
__global__ __launch_bounds__(256) void transpose_v(const u16* __restrict__ V,
                                                   u16* __restrict__ Vt) {
  const int st = blockIdx.x, bh = blockIdx.y;
  const int b = bh >> 4, h = bh & 15;
  __shared__ u16 tile[64][72];
  const int tid = threadIdx.x;
#pragma unroll
  for (int c = 0; c < 2; ++c) {
    int s = c*32 + (tid >> 3);
    int d0 = (tid & 7) * 8;
    *(uint4*)&tile[s][d0] =
        *(const uint4*)&V[((size_t)(b*S_ + st*64 + s)*H_ + h)*DK_ + d0];
  }
  __syncthreads();
#pragma unroll
  for (int c = 0; c < 2; ++c) {
    int d = c*32 + (tid >> 3);
    int s0 = (tid & 7) * 8;
    uint4 ov;
    u16* tp = (u16*)&ov;
#pragma unroll
    for (int jj = 0; jj < 8; ++jj) tp[jj] = tile[s0 + jj][d];
    *(uint4*)&Vt[((size_t)(bh*DK_ + d))*S_ + st*64 + s0] = ov;
  }
}

// ---------------- causal flash attention ----------------
// grid (S/64 q-tiles, B*H). 4 waves; wave w owns q rows [qt*64+w*16, +16).
// K tile [64 kv][64 dk], Vt tile [64 dk][64 kv] in LDS, XOR-swizzled (col8 ^ row&7).
__global__ __launch_bounds__(256) void attn_kernel(
    const u16* __restrict__ Q, const u16* __restrict__ K, const u16* __restrict__ Vt,
    u16* __restrict__ AO) {
  const int qt = blockIdx.x, bh = blockIdx.y;
  const int b = bh >> 4, h = bh & 15;
  const int tid = threadIdx.x, w = tid >> 6, lane = tid & 63;
  const int lo = lane & 15, hi = lane >> 4;

  __shared__ u16 Kl[64*64];
  __shared__ u16 Vl[64*64];
  __shared__ u16 Pl[4][16*72];

  const int qrow = qt*64 + w*16 + lo;
  bf16x8 qf[2];
#pragma unroll
  for (int kk = 0; kk < 2; ++kk)
    qf[kk] = *(const bf16x8*)&Q[((size_t)(b*S_ + qrow)*H_ + h)*DK_ + kk*32 + hi*8];

  f32x4 o[4] = {};
  float mr[4] = {-INFINITY, -INFINITY, -INFINITY, -INFINITY};
  float lr[4] = {0.f, 0.f, 0.f, 0.f};

  for (int kt = 0; kt <= qt; ++kt) {
    __syncthreads();
#pragma unroll
    for (int c = 0; c < 2; ++c) {
      int row = c*32 + (tid >> 3);
      int c8 = tid & 7;
      int sw = ((c8 ^ (row & 7)) * 8);
      *(uint4*)&Kl[row*64 + sw] =
          *(const uint4*)&K[((size_t)(b*S_ + kt*64 + row)*H_ + h)*DK_ + c8*8];
      *(uint4*)&Vl[row*64 + sw] =
          *(const uint4*)&Vt[((size_t)(bh*DK_ + row))*S_ + kt*64 + c8*8];
    }
    __syncthreads();

    // S = Q K^T  (rows: q = hi*4+j, cols: kv = n*16+lo)
    f32x4 s[4] = {};
#pragma unroll
    for (int kk = 0; kk < 2; ++kk) {
#pragma unroll
      for (int n = 0; n < 4; ++n) {
        int row = n*16 + lo;
        bf16x8 kf = *(const bf16x8*)&Kl[row*64 + (((kk*4 + hi) ^ (row & 7)) * 8)];
        s[n] = __builtin_amdgcn_mfma_f32_16x16x32_bf16(qf[kk], kf, s[n], 0, 0, 0);
      }
    }

    const bool diag = (kt == qt);
    float pm[4] = {-INFINITY, -INFINITY, -INFINITY, -INFINITY};
#pragma unroll
    for (int n = 0; n < 4; ++n) {
#pragma unroll
      for (int j = 0; j < 4; ++j) {
        float sv = s[n][j] * 0.125f;  // 1/sqrt(64)
        if (diag) {
          int colg = n*16 + lo;
          int rowg = w*16 + hi*4 + j;
          if (colg > rowg) sv = -INFINITY;
        }
        s[n][j] = sv;
        pm[j] = fmaxf(pm[j], sv);
      }
    }
#pragma unroll
    for (int d = 1; d < 16; d <<= 1)
#pragma unroll
      for (int j = 0; j < 4; ++j)
        pm[j] = fmaxf(pm[j], __shfl_xor(pm[j], d, 64));

    float corr[4];
#pragma unroll
    for (int j = 0; j < 4; ++j) {
      float mn = fmaxf(mr[j], pm[j]);
      corr[j] = __expf(mr[j] - mn);
      mr[j] = mn;
    }
    float rs[4] = {0.f, 0.f, 0.f, 0.f};
#pragma unroll
    for (int n = 0; n < 4; ++n)
#pragma unroll
      for (int j = 0; j < 4; ++j) {
        float p = __expf(s[n][j] - mr[j]);
        rs[j] += p;
        Pl[w][(hi*4 + j)*72 + n*16 + lo] = f2bf(p);
      }
#pragma unroll
    for (int d = 1; d < 16; d <<= 1)
#pragma unroll
      for (int j = 0; j < 4; ++j)
        rs[j] += __shfl_xor(rs[j], d, 64);
#pragma unroll
    for (int j = 0; j < 4; ++j)
      lr[j] = lr[j]*corr[j] + rs[j];
#pragma unroll
    for (int n = 0; n < 4; ++n)
#pragma unroll
      for (int j = 0; j < 4; ++j)
        o[n][j] *= corr[j];

    // O += P V   (A-frag from Pl, B-frag from Vl)
#pragma unroll
    for (int kk = 0; kk < 2; ++kk) {
      bf16x8 pf = *(const bf16x8*)&Pl[w][lo*72 + kk*32 + hi*8];
#pragma unroll
      for (int n = 0; n < 4; ++n) {
        int row = n*16 + lo;
        bf16x8 vf = *(const bf16x8*)&Vl[row*64 + (((kk*4 + hi) ^ (row & 7)) * 8)];
        o[n] = __builtin_amdgcn_mfma_f32_16x16x32_bf16(pf, vf, o[n], 0, 0, 0);
      }
    }
  }

#pragma unroll
  for (int n = 0; n < 4; ++n)
#pragma unroll
    for (int j = 0; j < 4; ++j) {
      int rowg = qt*64 + w*16 + hi*4 + j;
      AO[((size_t)(b*S_ + rowg)*H_ + h)*DK_ + n*16 + lo] = f2bf(o[n][j] / lr[j]);
    }
}

extern "C" void kernel_launch(void* const* d_in, const int* in_sizes, int n_in,
                              void* d_out, int out_size, void* d_ws, size_t ws_size,
                              hipStream_t stream) {
  const float* x  = (const float*)d_in[0];
  const float* Wq = (const float*)d_in[1];
  const float* bq = (const float*)d_in[2];
  const float* Wk = (const float*)d_in[3];
  const float* bk = (const float*)d_in[4];
  const float* Wv = (const float*)d_in[5];
  const float* bv = (const float*)d_in[6];
  const float* Wo = (const float*)d_in[7];
  const float* bo = (const float*)d_in[8];

  char* ws = (char*)d_ws;
  const size_t MB = 1048576;
  u16* xb  = (u16*)(ws + 0);        // 8 MiB
  u16* Wqb = (u16*)(ws + 8*MB);     // 2 MiB
  u16* Wkb = (u16*)(ws + 10*MB);
  u16* Wvb = (u16*)(ws + 12*MB);
  u16* Wob = (u16*)(ws + 14*MB);
  u16* Qb  = (u16*)(ws + 16*MB);    // 8 MiB
  u16* Kb  = (u16*)(ws + 24*MB);    // 8 MiB
  u16* Vb  = (u16*)(ws + 32*MB);    // 8 MiB
  u16* Vtb = (u16*)(ws + 0);        // reuses xb slot (x dead after projections)
  u16* AOb = (u16*)(ws + 32*MB);    // reuses V slot (V dead after transpose)

  f2bf_kernel<<<4096, 256, 0, stream>>>(x,  xb,  (M_*D_)/4);
  f2bf_kernel<<<1024, 256, 0, stream>>>(Wq, Wqb, (D_*D_)/4);
  f2bf_kernel<<<1024, 256, 0, stream>>>(Wk, Wkb, (D_*D_)/4);
  f2bf_kernel<<<1024, 256, 0, stream>>>(Wv, Wvb, (D_*D_)/4);
  f2bf_kernel<<<1024, 256, 0, stream>>>(Wo, Wob, (D_*D_)/4);

  // fused QKV projection: grid.z selects {Q,K,V}
  gemm_bt<false, true><<<dim3(8, 32, 3), 256, 0, stream>>>(
      xb, Wqb, Wkb, Wvb, bq, bk, bv, Qb, Kb, Vb, M_, D_, D_);

  transpose_v<<<dim3(32, 32), 256, 0, stream>>>(Vb, Vtb);

  attn_kernel<<<dim3(32, 32), 256, 0, stream>>>(Qb, Kb, Vtb, AOb);

  gemm_bt<true, false><<<dim3(8, 32, 1), 256, 0, stream>>>(
      AOb, Wob, nullptr, nullptr, bo, nullptr, nullptr,
      d_out, nullptr, nullptr, M_, D_, D_);
}

// Round 2
// 169.181 us; speedup vs baseline: 1.1797x; 1.1797x over previous
//
#include <hip/hip_runtime.h>
#include <stdint.h>
#include <math.h>

#define B_ 2
#define S_ 2048
#define D_ 1024
#define H_ 16
#define DK_ 64
#define M_ (B_*S_)   // 4096

typedef unsigned short u16;
typedef unsigned int u32;
typedef __attribute__((ext_vector_type(8))) __bf16 bf16x8;
typedef __attribute__((ext_vector_type(4))) float f32x4;

#define AS1 __attribute__((address_space(1)))
#define AS3 __attribute__((address_space(3)))

__device__ __forceinline__ u16 f2bf(float f) {
  u32 u = __float_as_uint(f);
  return (u16)((u + 0x7fffu + ((u >> 16) & 1u)) >> 16);  // RNE
}
__device__ __forceinline__ u16 f2bfr(float f) {          // round-half-up (p>=0)
  return (u16)((__float_as_uint(f) + 0x8000u) >> 16);
}

__device__ __forceinline__ void gload_lds16(const void* g, void* lds) {
  __builtin_amdgcn_global_load_lds((const AS1 u32*)g,
                                   (AS3 u32*)(u32)(uintptr_t)lds, 16, 0, 0);
}

// ---------------- fp32 -> bf16 convert (vectorized) ----------------
__global__ __launch_bounds__(256) void f2bf_kernel(const float* __restrict__ in,
                                                   u16* __restrict__ out, int n4) {
  int i = blockIdx.x * 256 + threadIdx.x;
  if (i >= n4) return;
  float4 v = ((const float4*)in)[i];
  u32 lo = (u32)f2bf(v.x) | ((u32)f2bf(v.y) << 16);
  u32 hi = (u32)f2bf(v.z) | ((u32)f2bf(v.w) << 16);
  ((uint2*)out)[i] = make_uint2(lo, hi);
}

// fused 4-weight convert (blockIdx.y selects matrix)
__global__ __launch_bounds__(256) void f2bf4_kernel(
    const float* __restrict__ W0, const float* __restrict__ W1,
    const float* __restrict__ W2, const float* __restrict__ W3,
    u16* __restrict__ o0, u16* __restrict__ o1, u16* __restrict__ o2, u16* __restrict__ o3,
    int n4) {
  const float* src; u16* dst;
  switch (blockIdx.y) {
    case 0: src = W0; dst = o0; break;
    case 1: src = W1; dst = o1; break;
    case 2: src = W2; dst = o2; break;
    default: src = W3; dst = o3; break;
  }
  int i = blockIdx.x * 256 + threadIdx.x;
  if (i >= n4) return;
  float4 v = ((const float4*)src)[i];
  u32 lo = (u32)f2bf(v.x) | ((u32)f2bf(v.y) << 16);
  u32 hi = (u32)f2bf(v.z) | ((u32)f2bf(v.w) << 16);
  ((uint2*)dst)[i] = make_uint2(lo, hi);
}

// ---------------- GEMM: C[m,n] = (sum_k A[m,k]*W[n,k] + bias[n]) * osc ----------------
// 128x128 tile, BK=32, 4 waves. QKV: grid.z selects {Q,K,V}; Q output pre-scaled
// by 0.125*log2(e) so attention softmax runs in exp2 domain with no per-score mul.
template <bool OUT_F32, bool QKV>
__global__ __launch_bounds__(256) void gemm_bt(
    const u16* __restrict__ A,
    const u16* __restrict__ W0, const u16* __restrict__ W1, const u16* __restrict__ W2,
    const float* __restrict__ b0, const float* __restrict__ b1, const float* __restrict__ b2,
    void* __restrict__ C0, void* __restrict__ C1, void* __restrict__ C2,
    int M, int N, int K) {
  const u16* W = W0; const float* bias = b0; void* Cv = C0;
  float osc = 1.0f;
  if (QKV) {
    if (blockIdx.z == 0)      { osc = 0.18033688f; }
    else if (blockIdx.z == 1) { W = W1; bias = b1; Cv = C1; }
    else                      { W = W2; bias = b2; Cv = C2; }
  }
  __shared__ u16 As[128*32];
  __shared__ u16 Bs[128*32];
  const int tid = threadIdx.x;
  const int wave = tid >> 6, lane = tid & 63;
  const int lo = lane & 15, hi = lane >> 4;
  const int wr = wave >> 1, wc = wave & 1;
  const int mbase = blockIdx.y * 128, nbase = blockIdx.x * 128;

  f32x4 acc[4][4] = {};

  for (int k0 = 0; k0 < K; k0 += 32) {
#pragma unroll
    for (int i = 0; i < 2; ++i) {
      int row = i*64 + (tid >> 2);
      int col = (tid & 3) * 8;
      gload_lds16(&A[(size_t)(mbase + row)*K + k0 + col], &As[row*32 + col]);
      gload_lds16(&W[(size_t)(nbase + row)*K + k0 + col], &Bs[row*32 + col]);
    }
    __syncthreads();
    bf16x8 af[4], bfr[4];
#pragma unroll
    for (int m = 0; m < 4; ++m)
      af[m] = *(const bf16x8*)&As[(wr*64 + m*16 + lo)*32 + hi*8];
#pragma unroll
    for (int n = 0; n < 4; ++n)
      bfr[n] = *(const bf16x8*)&Bs[(wc*64 + n*16 + lo)*32 + hi*8];
#pragma unroll
    for (int m = 0; m < 4; ++m)
#pragma unroll
      for (int n = 0; n < 4; ++n)
        acc[m][n] = __builtin_amdgcn_mfma_f32_16x16x32_bf16(af[m], bfr[n], acc[m][n], 0, 0, 0);
    __syncthreads();
  }

#pragma unroll
  for (int n = 0; n < 4; ++n) {
    int col = nbase + wc*64 + n*16 + lo;
    float bv = bias[col];
#pragma unroll
    for (int m = 0; m < 4; ++m) {
#pragma unroll
      for (int j = 0; j < 4; ++j) {
        int row = mbase + wr*64 + m*16 + hi*4 + j;
        float v = (acc[m][n][j] + bv) * osc;
        if constexpr (OUT_F32) ((float*)Cv)[(size_t)row*N + col] = v;
        else                   ((u16*)Cv)[(size_t)row*N + col] = f2bf(v);
      }
    }
  }
}

// ---------------- GEMM 64x128 tile (more blocks for the out-projection) ----------------
__global__ __launch_bounds__(256) void gemm_bt64(
    const u16* __restrict__ A, const u16* __restrict__ W,
    const float* __restrict__ bias, float* __restrict__ C,
    int M, int N, int K) {
  __shared__ u16 As[64*32];
  __shared__ u16 Bs[128*32];
  const int tid = threadIdx.x;
  const int wave = tid >> 6, lane = tid & 63;
  const int lo = lane & 15, hi = lane >> 4;
  const int mbase = blockIdx.y * 64, nbase = blockIdx.x * 128;

  f32x4 acc[4][2] = {};

  for (int k0 = 0; k0 < K; k0 += 32) {
    {
      int row = tid >> 2;
      int col = (tid & 3) * 8;
      gload_lds16(&A[(size_t)(mbase + row)*K + k0 + col], &As[row*32 + col]);
#pragma unroll
      for (int i = 0; i < 2; ++i)
        gload_lds16(&W[(size_t)(nbase + i*64 + row)*K + k0 + col], &Bs[(i*64 + row)*32 + col]);
    }
    __syncthreads();
    bf16x8 af[4], bfr[2];
#pragma unroll
    for (int m = 0; m < 4; ++m)
      af[m] = *(const bf16x8*)&As[(m*16 + lo)*32 + hi*8];
#pragma unroll
    for (int n = 0; n < 2; ++n)
      bfr[n] = *(const bf16x8*)&Bs[(wave*32 + n*16 + lo)*32 + hi*8];
#pragma unroll
    for (int m = 0; m < 4; ++m)
#pragma unroll
      for (int n = 0; n < 2; ++n)
        acc[m][n] = __builtin_amdgcn_mfma_f32_16x16x32_bf16(af[m], bfr[n], acc[m][n], 0, 0, 0);
    __syncthreads();
  }

#pragma unroll
  for (int n = 0; n < 2; ++n) {
    int col = nbase + wave*32 + n*16 + lo;
    float bv = bias[col];
#pragma unroll
    for (int m = 0; m < 4; ++m)
#pragma unroll
      for (int j = 0; j < 4; ++j) {
        int row = mbase + m*16 + hi*4 + j;
        C[(size_t)row*N + col] = acc[m][n][j] + bv;
      }
  }
}

// ---------------- V [B,S,H,DK] -> Vt [B,H,DK,S] ----------------
__global__ __launch_bounds__(256) void transpose_v(const u16* __restrict__ V,
                                                   u16* __restrict__ Vt) {
  const int st = blockIdx.x, bh = blockIdx.y;
  const int b = bh >> 4, h = bh & 15;
  __shared__ u16 tile[64][72];
  const int tid = threadIdx.x;
#pragma unroll
  for (int c = 0; c < 2; ++c) {
    int s = c*32 + (tid >> 3);
    int d0 = (tid & 7) * 8;
    *(uint4*)&tile[s][d0] =
        *(const uint4*)&V[((size_t)(b*S_ + st*64 + s))*D_ + h*DK_ + d0];
  }
  __syncthreads();
#pragma unroll
  for (int c = 0; c < 2; ++c) {
    int d = c*32 + (tid >> 3);
    int s0 = (tid & 7) * 8;
    uint4 ov;
    u16* tp = (u16*)&ov;
#pragma unroll
    for (int jj = 0; jj < 8; ++jj) tp[jj] = tile[s0 + jj][d];
    *(uint4*)&Vt[((size_t)(bh*DK_ + d))*S_ + st*64 + s0] = ov;
  }
}

// ---------------- causal flash attention, swapped-QK^T, balanced pairs ----------------
// grid (16 qtile-pairs, B*H). Block handles q-tiles {qp, 31-qp}: 33 kv-iters always.
// 4 waves; wave w owns q rows [qt*64+w*16, +16). Swapped S=mfma(K,Q): lane holds 16
// scores of ONE q-row (q=lane&15) -> scalar m/l state, 2-shuffle reduces, b64 P writes.
// K/V double-buffered in LDS (XOR swizzle), register prefetch, 1 barrier/iter.
__global__ __launch_bounds__(256) void attn_kernel(
    const u16* __restrict__ Q, const u16* __restrict__ K, const u16* __restrict__ Vt,
    u16* __restrict__ AO) {
  const int qp = blockIdx.x, bh = blockIdx.y;
  const int b = bh >> 4, h = bh & 15;
  const int tid = threadIdx.x, w = tid >> 6, lane = tid & 63;
  const int lo = lane & 15, hi = lane >> 4;

  __shared__ u16 Kl[2][64*64];
  __shared__ u16 Vl[2][64*64];
  __shared__ u16 Pl[4][16*72];

  const int srow = tid >> 3;   // 0..31
  const int c8 = tid & 7;      // 0..7 (16B column chunk)
  const size_t kbase = (size_t)b*S_*D_ + (size_t)h*DK_;
  const size_t vbase = (size_t)bh*DK_*S_;

  for (int pass = 0; pass < 2; ++pass) {
    const int qt = pass ? (31 - qp) : qp;
    const int qrow = qt*64 + w*16 + lo;
    bf16x8 qf[2];
#pragma unroll
    for (int kk = 0; kk < 2; ++kk)
      qf[kk] = *(const bf16x8*)&Q[(size_t)(b*S_ + qrow)*D_ + h*DK_ + kk*32 + hi*8];

    f32x4 o[4] = {};
    float mr = -INFINITY, lr = 0.f;

    // prefetch kv-tile 0 into registers
    uint4 kd[2], vd[2];
#pragma unroll
    for (int c = 0; c < 2; ++c) {
      int row = c*32 + srow;
      kd[c] = *(const uint4*)&K[kbase + (size_t)row*D_ + c8*8];
      vd[c] = *(const uint4*)&Vt[vbase + (size_t)row*S_ + c8*8];
    }

    __syncthreads();  // pass guard: previous pass done with LDS buffers

    for (int kt = 0; kt <= qt; ++kt) {
      const int cur = kt & 1;
      // stage prefetched regs -> LDS (XOR swizzled)
#pragma unroll
      for (int c = 0; c < 2; ++c) {
        int row = c*32 + srow;
        int sw = ((c8 ^ (row & 7)) * 8);
        *(uint4*)&Kl[cur][row*64 + sw] = kd[c];
        *(uint4*)&Vl[cur][row*64 + sw] = vd[c];
      }
      __syncthreads();
      if (kt < qt) {
#pragma unroll
        for (int c = 0; c < 2; ++c) {
          int row = c*32 + srow;
          kd[c] = *(const uint4*)&K[kbase + (size_t)((kt+1)*64 + row)*D_ + c8*8];
          vd[c] = *(const uint4*)&Vt[vbase + (size_t)row*S_ + (kt+1)*64 + c8*8];
        }
      }

      // S^T = K Q^T : lane holds s[n][j] = score(q=lo, kv=n*16+hi*4+j)
      f32x4 s[4] = {};
#pragma unroll
      for (int kk = 0; kk < 2; ++kk) {
#pragma unroll
        for (int n = 0; n < 4; ++n) {
          int row = n*16 + lo;
          bf16x8 kf = *(const bf16x8*)&Kl[cur][row*64 + (((kk*4 + hi) ^ (row & 7)) * 8)];
          s[n] = __builtin_amdgcn_mfma_f32_16x16x32_bf16(kf, qf[kk], s[n], 0, 0, 0);
        }
      }

      if (kt == qt) {  // causal mask on diagonal tile
        const int ql = w*16 + lo;
#pragma unroll
        for (int n = 0; n < 4; ++n)
#pragma unroll
          for (int j = 0; j < 4; ++j)
            if (n*16 + hi*4 + j > ql) s[n][j] = -INFINITY;
      }

      float pm = -INFINITY;
#pragma unroll
      for (int n = 0; n < 4; ++n)
#pragma unroll
        for (int j = 0; j < 4; ++j) pm = fmaxf(pm, s[n][j]);
      pm = fmaxf(pm, __shfl_xor(pm, 16));
      pm = fmaxf(pm, __shfl_xor(pm, 32));

      if (!__all(pm <= mr + 11.0f)) {   // defer-max: rescale rarely
        float mn = fmaxf(mr, pm);
        float corr = __builtin_amdgcn_exp2f(mr - mn);
        mr = mn;
        lr *= corr;
        float cj[4];
#pragma unroll
        for (int j = 0; j < 4; ++j) cj[j] = __shfl(corr, hi*4 + j);
#pragma unroll
        for (int n = 0; n < 4; ++n)
#pragma unroll
          for (int j = 0; j < 4; ++j) o[n][j] *= cj[j];
      }

      float rs = 0.f;
#pragma unroll
      for (int n = 0; n < 4; ++n) {
        float p0 = __builtin_amdgcn_exp2f(s[n][0] - mr);
        float p1 = __builtin_amdgcn_exp2f(s[n][1] - mr);
        float p2 = __builtin_amdgcn_exp2f(s[n][2] - mr);
        float p3 = __builtin_amdgcn_exp2f(s[n][3] - mr);
        rs += (p0 + p1) + (p2 + p3);
        u32 d01 = (u32)f2bfr(p0) | ((u32)f2bfr(p1) << 16);
        u32 d23 = (u32)f2bfr(p2) | ((u32)f2bfr(p3) << 16);
        *(uint2*)&Pl[w][lo*72 + n*16 + hi*4] = make_uint2(d01, d23);
      }
      rs += __shfl_xor(rs, 16);
      rs += __shfl_xor(rs, 32);
      lr += rs;

      // O += P V
#pragma unroll
      for (int kk = 0; kk < 2; ++kk) {
        bf16x8 pf = *(const bf16x8*)&Pl[w][lo*72 + kk*32 + hi*8];
#pragma unroll
        for (int n = 0; n < 4; ++n) {
          int row = n*16 + lo;
          bf16x8 vf = *(const bf16x8*)&Vl[cur][row*64 + (((kk*4 + hi) ^ (row & 7)) * 8)];
          o[n] = __builtin_amdgcn_mfma_f32_16x16x32_bf16(pf, vf, o[n], 0, 0, 0);
        }
      }
    }

    float lrj[4];
#pragma unroll
    for (int j = 0; j < 4; ++j) lrj[j] = __shfl(lr, hi*4 + j);
#pragma unroll
    for (int n = 0; n < 4; ++n)
#pragma unroll
      for (int j = 0; j < 4; ++j) {
        int rowg = qt*64 + w*16 + hi*4 + j;
        AO[(size_t)(b*S_ + rowg)*D_ + h*DK_ + n*16 + lo] = f2bf(o[n][j] / lrj[j]);
      }
  }
}

extern "C" void kernel_launch(void* const* d_in, const int* in_sizes, int n_in,
                              void* d_out, int out_size, void* d_ws, size_t ws_size,
                              hipStream_t stream) {
  const float* x  = (const float*)d_in[0];
  const float* Wq = (const float*)d_in[1];
  const float* bq = (const float*)d_in[2];
  const float* Wk = (const float*)d_in[3];
  const float* bk = (const float*)d_in[4];
  const float* Wv = (const float*)d_in[5];
  const float* bv = (const float*)d_in[6];
  const float* Wo = (const float*)d_in[7];
  const float* bo = (const float*)d_in[8];

  char* ws = (char*)d_ws;
  const size_t MB = 1048576;
  u16* xb  = (u16*)(ws + 0);        // 8 MiB
  u16* Wqb = (u16*)(ws + 8*MB);     // 2 MiB each
  u16* Wkb = (u16*)(ws + 10*MB);
  u16* Wvb = (u16*)(ws + 12*MB);
  u16* Wob = (u16*)(ws + 14*MB);
  u16* Qb  = (u16*)(ws + 16*MB);    // 8 MiB
  u16* Kb  = (u16*)(ws + 24*MB);    // 8 MiB
  u16* Vb  = (u16*)(ws + 32*MB);    // 8 MiB
  u16* Vtb = (u16*)(ws + 0);        // reuses xb slot (x dead after projections)
  u16* AOb = (u16*)(ws + 32*MB);    // reuses V slot (V dead after transpose)

  f2bf_kernel<<<4096, 256, 0, stream>>>(x, xb, (M_*D_)/4);
  f2bf4_kernel<<<dim3(1024, 4), 256, 0, stream>>>(Wq, Wk, Wv, Wo,
                                                  Wqb, Wkb, Wvb, Wob, (D_*D_)/4);

  gemm_bt<false, true><<<dim3(8, 32, 3), 256, 0, stream>>>(
      xb, Wqb, Wkb, Wvb, bq, bk, bv, Qb, Kb, Vb, M_, D_, D_);

  transpose_v<<<dim3(32, 32), 256, 0, stream>>>(Vb, Vtb);

  attn_kernel<<<dim3(16, 32), 256, 0, stream>>>(Qb, Kb, Vtb, AOb);

  gemm_bt64<<<dim3(8, 64), 256, 0, stream>>>(AOb, Wob, bo, (float*)d_out, M_, D_, D_);
}

// Round 3
// 163.552 us; speedup vs baseline: 1.2203x; 1.0344x over previous
//
#include <hip/hip_runtime.h>
#include <stdint.h>
#include <math.h>

#define B_ 2
#define S_ 2048
#define D_ 1024
#define H_ 16
#define DK_ 64
#define M_ (B_*S_)   // 4096

typedef unsigned short u16;
typedef unsigned int u32;
typedef __attribute__((ext_vector_type(8))) __bf16 bf16x8;
typedef __attribute__((ext_vector_type(4))) float f32x4;

#define AS1 __attribute__((address_space(1)))
#define AS3 __attribute__((address_space(3)))

__device__ __forceinline__ u16 f2bf(float f) {
  u32 u = __float_as_uint(f);
  return (u16)((u + 0x7fffu + ((u >> 16) & 1u)) >> 16);  // RNE
}
__device__ __forceinline__ u16 f2bfr(float f) {          // round-half-up (p>=0)
  return (u16)((__float_as_uint(f) + 0x8000u) >> 16);
}

__device__ __forceinline__ void gload_lds16(const void* g, void* lds) {
  __builtin_amdgcn_global_load_lds((const AS1 u32*)g,
                                   (AS3 u32*)(u32)(uintptr_t)lds, 16, 0, 0);
}

// ---------------- fp32 -> bf16 convert (vectorized) ----------------
__global__ __launch_bounds__(256) void f2bf_kernel(const float* __restrict__ in,
                                                   u16* __restrict__ out, int n4) {
  int i = blockIdx.x * 256 + threadIdx.x;
  if (i >= n4) return;
  float4 v = ((const float4*)in)[i];
  u32 lo = (u32)f2bf(v.x) | ((u32)f2bf(v.y) << 16);
  u32 hi = (u32)f2bf(v.z) | ((u32)f2bf(v.w) << 16);
  ((uint2*)out)[i] = make_uint2(lo, hi);
}

// fused 4-weight convert (blockIdx.y selects matrix)
__global__ __launch_bounds__(256) void f2bf4_kernel(
    const float* __restrict__ W0, const float* __restrict__ W1,
    const float* __restrict__ W2, const float* __restrict__ W3,
    u16* __restrict__ o0, u16* __restrict__ o1, u16* __restrict__ o2, u16* __restrict__ o3,
    int n4) {
  const float* src; u16* dst;
  switch (blockIdx.y) {
    case 0: src = W0; dst = o0; break;
    case 1: src = W1; dst = o1; break;
    case 2: src = W2; dst = o2; break;
    default: src = W3; dst = o3; break;
  }
  int i = blockIdx.x * 256 + threadIdx.x;
  if (i >= n4) return;
  float4 v = ((const float4*)src)[i];
  u32 lo = (u32)f2bf(v.x) | ((u32)f2bf(v.y) << 16);
  u32 hi = (u32)f2bf(v.z) | ((u32)f2bf(v.w) << 16);
  ((uint2*)dst)[i] = make_uint2(lo, hi);
}

// ---------------- GEMM: C[m,n] = (sum_k A[m,k]*W[n,k] + bias[n]) * osc ----------------
template <bool OUT_F32, bool QKV>
__global__ __launch_bounds__(256) void gemm_bt(
    const u16* __restrict__ A,
    const u16* __restrict__ W0, const u16* __restrict__ W1, const u16* __restrict__ W2,
    const float* __restrict__ b0, const float* __restrict__ b1, const float* __restrict__ b2,
    void* __restrict__ C0, void* __restrict__ C1, void* __restrict__ C2,
    int M, int N, int K) {
  const u16* W = W0; const float* bias = b0; void* Cv = C0;
  float osc = 1.0f;
  if (QKV) {
    if (blockIdx.z == 0)      { osc = 0.18033688f; }   // 0.125 * log2(e)
    else if (blockIdx.z == 1) { W = W1; bias = b1; Cv = C1; }
    else                      { W = W2; bias = b2; Cv = C2; }
  }
  __shared__ u16 As[128*32];
  __shared__ u16 Bs[128*32];
  const int tid = threadIdx.x;
  const int wave = tid >> 6, lane = tid & 63;
  const int lo = lane & 15, hi = lane >> 4;
  const int wr = wave >> 1, wc = wave & 1;
  const int mbase = blockIdx.y * 128, nbase = blockIdx.x * 128;

  f32x4 acc[4][4] = {};

  for (int k0 = 0; k0 < K; k0 += 32) {
#pragma unroll
    for (int i = 0; i < 2; ++i) {
      int row = i*64 + (tid >> 2);
      int col = (tid & 3) * 8;
      gload_lds16(&A[(size_t)(mbase + row)*K + k0 + col], &As[row*32 + col]);
      gload_lds16(&W[(size_t)(nbase + row)*K + k0 + col], &Bs[row*32 + col]);
    }
    __syncthreads();
    bf16x8 af[4], bfr[4];
#pragma unroll
    for (int m = 0; m < 4; ++m)
      af[m] = *(const bf16x8*)&As[(wr*64 + m*16 + lo)*32 + hi*8];
#pragma unroll
    for (int n = 0; n < 4; ++n)
      bfr[n] = *(const bf16x8*)&Bs[(wc*64 + n*16 + lo)*32 + hi*8];
#pragma unroll
    for (int m = 0; m < 4; ++m)
#pragma unroll
      for (int n = 0; n < 4; ++n)
        acc[m][n] = __builtin_amdgcn_mfma_f32_16x16x32_bf16(af[m], bfr[n], acc[m][n], 0, 0, 0);
    __syncthreads();
  }

#pragma unroll
  for (int n = 0; n < 4; ++n) {
    int col = nbase + wc*64 + n*16 + lo;
    float bv = bias[col];
#pragma unroll
    for (int m = 0; m < 4; ++m) {
#pragma unroll
      for (int j = 0; j < 4; ++j) {
        int row = mbase + wr*64 + m*16 + hi*4 + j;
        float v = (acc[m][n][j] + bv) * osc;
        if constexpr (OUT_F32) ((float*)Cv)[(size_t)row*N + col] = v;
        else                   ((u16*)Cv)[(size_t)row*N + col] = f2bf(v);
      }
    }
  }
}

// ---------------- GEMM 64x128 tile (out-projection) ----------------
__global__ __launch_bounds__(256) void gemm_bt64(
    const u16* __restrict__ A, const u16* __restrict__ W,
    const float* __restrict__ bias, float* __restrict__ C,
    int M, int N, int K) {
  __shared__ u16 As[64*32];
  __shared__ u16 Bs[128*32];
  const int tid = threadIdx.x;
  const int wave = tid >> 6, lane = tid & 63;
  const int lo = lane & 15, hi = lane >> 4;
  const int mbase = blockIdx.y * 64, nbase = blockIdx.x * 128;

  f32x4 acc[4][2] = {};

  for (int k0 = 0; k0 < K; k0 += 32) {
    {
      int row = tid >> 2;
      int col = (tid & 3) * 8;
      gload_lds16(&A[(size_t)(mbase + row)*K + k0 + col], &As[row*32 + col]);
#pragma unroll
      for (int i = 0; i < 2; ++i)
        gload_lds16(&W[(size_t)(nbase + i*64 + row)*K + k0 + col], &Bs[(i*64 + row)*32 + col]);
    }
    __syncthreads();
    bf16x8 af[4], bfr[2];
#pragma unroll
    for (int m = 0; m < 4; ++m)
      af[m] = *(const bf16x8*)&As[(m*16 + lo)*32 + hi*8];
#pragma unroll
    for (int n = 0; n < 2; ++n)
      bfr[n] = *(const bf16x8*)&Bs[(wave*32 + n*16 + lo)*32 + hi*8];
#pragma unroll
    for (int m = 0; m < 4; ++m)
#pragma unroll
      for (int n = 0; n < 2; ++n)
        acc[m][n] = __builtin_amdgcn_mfma_f32_16x16x32_bf16(af[m], bfr[n], acc[m][n], 0, 0, 0);
    __syncthreads();
  }

#pragma unroll
  for (int n = 0; n < 2; ++n) {
    int col = nbase + wave*32 + n*16 + lo;
    float bv = bias[col];
#pragma unroll
    for (int m = 0; m < 4; ++m)
#pragma unroll
      for (int j = 0; j < 4; ++j) {
        int row = mbase + m*16 + hi*4 + j;
        C[(size_t)row*N + col] = acc[m][n][j] + bv;
      }
  }
}

// ---------------- V [B,S,D] (head-sliced) -> Vt [B,H,DK,S] ----------------
__global__ __launch_bounds__(256) void transpose_v(const u16* __restrict__ V,
                                                   u16* __restrict__ Vt) {
  const int st = blockIdx.x, bh = blockIdx.y;
  const int b = bh >> 4, h = bh & 15;
  __shared__ u16 tile[64][72];
  const int tid = threadIdx.x;
#pragma unroll
  for (int c = 0; c < 2; ++c) {
    int s = c*32 + (tid >> 3);
    int d0 = (tid & 7) * 8;
    *(uint4*)&tile[s][d0] =
        *(const uint4*)&V[((size_t)(b*S_ + st*64 + s))*D_ + h*DK_ + d0];
  }
  __syncthreads();
#pragma unroll
  for (int c = 0; c < 2; ++c) {
    int d = c*32 + (tid >> 3);
    int s0 = (tid & 7) * 8;
    uint4 ov;
    u16* tp = (u16*)&ov;
#pragma unroll
    for (int jj = 0; jj < 8; ++jj) tp[jj] = tile[s0 + jj][d];
    *(uint4*)&Vt[((size_t)(bh*DK_ + d))*S_ + st*64 + s0] = ov;
  }
}

// ---------------- causal flash attention ----------------
// 1D grid 512, XCD-clustered: xcd=blk&7 serves 4 bh (K/V working set 2MB < 4MB L2).
// Block handles q-tiles {qp, 31-qp}: 33 kv-iters balanced. Swapped QK^T: lane holds
// scores for q=lane&15 -> per-lane m/l state, ZERO shuffles in common path (defer-max
// on per-lane partials, l reduced once at end). Prefetch depth 2 (named reg buffers),
// K/V double-buffered in LDS with XOR swizzle, 1 barrier/iter.
#define ATTN_STEP(KT, KD, VD, BUF) do {                                          \
    const int kt_ = (KT);                                                        \
    _Pragma("unroll")                                                            \
    for (int c = 0; c < 2; ++c) {                                                \
      int row = c*32 + srow;                                                     \
      int sw = (c8 ^ (row & 7)) * 8;                                             \
      *(uint4*)&Kl[BUF][row*64 + sw] = KD[c];                                    \
      *(uint4*)&Vl[BUF][row*64 + sw] = VD[c];                                    \
    }                                                                            \
    __syncthreads();                                                             \
    if (kt_ + 2 <= qt) {                                                         \
      _Pragma("unroll")                                                          \
      for (int c = 0; c < 2; ++c) {                                              \
        int row = c*32 + srow;                                                   \
        KD[c] = *(const uint4*)&K[kbase + (size_t)((kt_+2)*64 + row)*D_ + c8*8]; \
        VD[c] = *(const uint4*)&Vt[vbase + (size_t)row*S_ + (kt_+2)*64 + c8*8];  \
      }                                                                          \
    }                                                                            \
    f32x4 s[4] = {};                                                             \
    _Pragma("unroll")                                                            \
    for (int kk = 0; kk < 2; ++kk) {                                             \
      _Pragma("unroll")                                                          \
      for (int n = 0; n < 4; ++n) {                                              \
        int row = n*16 + lo;                                                     \
        bf16x8 kf = *(const bf16x8*)&Kl[BUF][row*64 + (((kk*4 + hi) ^ (row & 7)) * 8)]; \
        s[n] = __builtin_amdgcn_mfma_f32_16x16x32_bf16(kf, qf[kk], s[n], 0, 0, 0); \
      }                                                                          \
    }                                                                            \
    if (kt_ == qt) {                                                             \
      const int ql = w*16 + lo;                                                  \
      _Pragma("unroll")                                                          \
      for (int n = 0; n < 4; ++n)                                                \
        _Pragma("unroll")                                                        \
        for (int j = 0; j < 4; ++j)                                              \
          if (n*16 + hi*4 + j > ql) s[n][j] = -INFINITY;                         \
    }                                                                            \
    float pm = -INFINITY;                                                        \
    _Pragma("unroll")                                                            \
    for (int n = 0; n < 4; ++n)                                                  \
      _Pragma("unroll")                                                          \
      for (int j = 0; j < 4; ++j) pm = fmaxf(pm, s[n][j]);                       \
    if (!__all(pm <= mr + 11.0f)) {                                              \
      pm = fmaxf(pm, __shfl_xor(pm, 16));                                        \
      pm = fmaxf(pm, __shfl_xor(pm, 32));                                        \
      float mn = fmaxf(mr, pm);                                                  \
      float corr = __builtin_amdgcn_exp2f(mr - mn);                              \
      mr = mn;                                                                   \
      lr *= corr;                                                                \
      float cj[4];                                                               \
      _Pragma("unroll")                                                          \
      for (int j = 0; j < 4; ++j) cj[j] = __shfl(corr, hi*4 + j);                \
      _Pragma("unroll")                                                          \
      for (int n = 0; n < 4; ++n)                                                \
        _Pragma("unroll")                                                        \
        for (int j = 0; j < 4; ++j) o[n][j] *= cj[j];                            \
    }                                                                            \
    _Pragma("unroll")                                                            \
    for (int n = 0; n < 4; ++n) {                                                \
      float p0 = __builtin_amdgcn_exp2f(s[n][0] - mr);                           \
      float p1 = __builtin_amdgcn_exp2f(s[n][1] - mr);                           \
      float p2 = __builtin_amdgcn_exp2f(s[n][2] - mr);                           \
      float p3 = __builtin_amdgcn_exp2f(s[n][3] - mr);                           \
      lr += (p0 + p1) + (p2 + p3);                                               \
      u32 d01 = (u32)f2bfr(p0) | ((u32)f2bfr(p1) << 16);                         \
      u32 d23 = (u32)f2bfr(p2) | ((u32)f2bfr(p3) << 16);                         \
      *(uint2*)&Pl[w][lo*72 + n*16 + hi*4] = make_uint2(d01, d23);               \
    }                                                                            \
    _Pragma("unroll")                                                            \
    for (int kk = 0; kk < 2; ++kk) {                                             \
      bf16x8 pf = *(const bf16x8*)&Pl[w][lo*72 + kk*32 + hi*8];                  \
      _Pragma("unroll")                                                          \
      for (int n = 0; n < 4; ++n) {                                              \
        int row = n*16 + lo;                                                     \
        bf16x8 vf = *(const bf16x8*)&Vl[BUF][row*64 + (((kk*4 + hi) ^ (row & 7)) * 8)]; \
        o[n] = __builtin_amdgcn_mfma_f32_16x16x32_bf16(pf, vf, o[n], 0, 0, 0);   \
      }                                                                          \
    }                                                                            \
  } while (0)

__global__ __launch_bounds__(256) void attn_kernel(
    const u16* __restrict__ Q, const u16* __restrict__ K, const u16* __restrict__ Vt,
    u16* __restrict__ AO) {
  const int blk = blockIdx.x;
  const int xcd = blk & 7, slot = blk >> 3;   // slot 0..63
  const int bh = xcd + 8*(slot & 3);          // 4 bh per XCD -> L2 K/V reuse
  const int qp = slot >> 2;                   // 0..15
  const int b = bh >> 4, h = bh & 15;
  const int tid = threadIdx.x, w = tid >> 6, lane = tid & 63;
  const int lo = lane & 15, hi = lane >> 4;

  __shared__ u16 Kl[2][64*64];
  __shared__ u16 Vl[2][64*64];
  __shared__ u16 Pl[4][16*72];

  const int srow = tid >> 3;   // 0..31
  const int c8 = tid & 7;      // 16B column chunk
  const size_t kbase = (size_t)b*S_*D_ + (size_t)h*DK_;
  const size_t vbase = (size_t)bh*DK_*S_;

  for (int pass = 0; pass < 2; ++pass) {
    const int qt = pass ? (31 - qp) : qp;
    const int qrow = qt*64 + w*16 + lo;
    bf16x8 qf[2];
#pragma unroll
    for (int kk = 0; kk < 2; ++kk)
      qf[kk] = *(const bf16x8*)&Q[(size_t)(b*S_ + qrow)*D_ + h*DK_ + kk*32 + hi*8];

    f32x4 o[4] = {};
    float mr = -INFINITY, lr = 0.f;

    // prologue: prefetch kv-tiles 0 and 1 into named register buffers
    uint4 kdA[2], vdA[2], kdB[2], vdB[2];
#pragma unroll
    for (int c = 0; c < 2; ++c) {
      int row = c*32 + srow;
      kdA[c] = *(const uint4*)&K[kbase + (size_t)row*D_ + c8*8];
      vdA[c] = *(const uint4*)&Vt[vbase + (size_t)row*S_ + c8*8];
    }
    if (qt > 0) {
#pragma unroll
      for (int c = 0; c < 2; ++c) {
        int row = c*32 + srow;
        kdB[c] = *(const uint4*)&K[kbase + (size_t)(64 + row)*D_ + c8*8];
        vdB[c] = *(const uint4*)&Vt[vbase + (size_t)row*S_ + 64 + c8*8];
      }
    }

    __syncthreads();  // pass guard: previous pass done with LDS buffers

    for (int kt = 0; ; kt += 2) {
      ATTN_STEP(kt, kdA, vdA, 0);
      if (kt + 1 > qt) break;
      ATTN_STEP(kt + 1, kdB, vdB, 1);
      if (kt + 2 > qt) break;
    }

    // reduce l across the 4 hi-lanes of each q-row, broadcast per output row
    lr += __shfl_xor(lr, 16);
    lr += __shfl_xor(lr, 32);
    float lrj[4];
#pragma unroll
    for (int j = 0; j < 4; ++j) lrj[j] = __shfl(lr, hi*4 + j);
#pragma unroll
    for (int n = 0; n < 4; ++n)
#pragma unroll
      for (int j = 0; j < 4; ++j) {
        int rowg = qt*64 + w*16 + hi*4 + j;
        AO[(size_t)(b*S_ + rowg)*D_ + h*DK_ + n*16 + lo] = f2bf(o[n][j] / lrj[j]);
      }
  }
}

extern "C" void kernel_launch(void* const* d_in, const int* in_sizes, int n_in,
                              void* d_out, int out_size, void* d_ws, size_t ws_size,
                              hipStream_t stream) {
  const float* x  = (const float*)d_in[0];
  const float* Wq = (const float*)d_in[1];
  const float* bq = (const float*)d_in[2];
  const float* Wk = (const float*)d_in[3];
  const float* bk = (const float*)d_in[4];
  const float* Wv = (const float*)d_in[5];
  const float* bv = (const float*)d_in[6];
  const float* Wo = (const float*)d_in[7];
  const float* bo = (const float*)d_in[8];

  char* ws = (char*)d_ws;
  const size_t MB = 1048576;
  u16* xb  = (u16*)(ws + 0);        // 8 MiB
  u16* Wqb = (u16*)(ws + 8*MB);     // 2 MiB each
  u16* Wkb = (u16*)(ws + 10*MB);
  u16* Wvb = (u16*)(ws + 12*MB);
  u16* Wob = (u16*)(ws + 14*MB);
  u16* Qb  = (u16*)(ws + 16*MB);    // 8 MiB
  u16* Kb  = (u16*)(ws + 24*MB);    // 8 MiB
  u16* Vb  = (u16*)(ws + 32*MB);    // 8 MiB
  u16* Vtb = (u16*)(ws + 0);        // reuses xb slot (x dead after projections)
  u16* AOb = (u16*)(ws + 32*MB);    // reuses V slot (V dead after transpose)

  f2bf_kernel<<<4096, 256, 0, stream>>>(x, xb, (M_*D_)/4);
  f2bf4_kernel<<<dim3(1024, 4), 256, 0, stream>>>(Wq, Wk, Wv, Wo,
                                                  Wqb, Wkb, Wvb, Wob, (D_*D_)/4);

  gemm_bt<false, true><<<dim3(8, 32, 3), 256, 0, stream>>>(
      xb, Wqb, Wkb, Wvb, bq, bk, bv, Qb, Kb, Vb, M_, D_, D_);

  transpose_v<<<dim3(32, 32), 256, 0, stream>>>(Vb, Vtb);

  attn_kernel<<<512, 256, 0, stream>>>(Qb, Kb, Vtb, AOb);

  gemm_bt64<<<dim3(8, 64), 256, 0, stream>>>(AOb, Wob, bo, (float*)d_out, M_, D_, D_);
}